// Round 3
// baseline (576.262 us; speedup 1.0000x reference)
//
#include <hip/hip_runtime.h>
#include <hip/hip_bf16.h>

typedef __bf16 bf16x8 __attribute__((ext_vector_type(8)));
typedef __bf16 bf16x4 __attribute__((ext_vector_type(4)));
typedef float floatx4 __attribute__((ext_vector_type(4)));
typedef float floatx4u __attribute__((ext_vector_type(4), aligned(4)));

// ---------------- prep: build Wp (bf16, A-operand order), effAB (bf16 B-operand), bias2 ----------------
__global__ void sgc_prep(const float* __restrict__ W, const float* __restrict__ b,
                         const float* __restrict__ A, const float* __restrict__ edge,
                         const float* __restrict__ adA,
                         __hip_bfloat16* __restrict__ Wp, __hip_bfloat16* __restrict__ effAB,
                         float* __restrict__ bias2) {
  int tid = blockIdx.x * blockDim.x + threadIdx.x;
  int nthr = gridDim.x * blockDim.x;
  // Wp[c*192 + k*64 + ci] = bf16(W[(k*128+c)*64 + ci])   (24576 elems)
  for (int i = tid; i < 24576; i += nthr) {
    int c = i / 192; int r = i - c * 192; int k = r >> 6; int ci = r & 63;
    Wp[i] = __float2bfloat16(W[(k * 128 + c) * 64 + ci]);
  }
  // effAB[n*32 + v] = bf16(effA[k=n/25][v][w=n%25]), n<75 && v<25, else 0  (2560 elems)
  for (int i = tid; i < 2560; i += nthr) {
    int n = i >> 5; int v = i & 31;
    float val = 0.f;
    if (n < 75 && v < 25) {
      int k = n / 25; int w = n - k * 25;
      int idx = (k * 25 + v) * 25 + w;
      val = A[idx] * edge[idx] + adA[idx];
    }
    effAB[i] = __float2bfloat16(val);
  }
  // bias2[c*25+w] = sum_k b[k*128+c] * sum_v effA[k][v][w]   (3200 elems, fp32 exact)
  for (int i = tid; i < 3200; i += nthr) {
    int c = i / 25; int w = i - c * 25;
    float s = 0.f;
    for (int k = 0; k < 3; k++) {
      float sv = 0.f;
      for (int v = 0; v < 25; v++) {
        int idx = (k * 25 + v) * 25 + w;
        sv += A[idx] * edge[idx] + adA[idx];
      }
      s += b[k * 128 + c] * sv;
    }
    bias2[i] = s;
  }
}

// ---------------- kernel 1: z[pixel][k*64+ci] = x @ effA  (no LDS, no barrier) ----------------
// One wave per pixel, 4 pixels per 256-thr block. z is B-operand-ordered bf16.
__global__ __launch_bounds__(256, 4)
void sgc_z(const float* __restrict__ x,
           const __hip_bfloat16* __restrict__ effAB,
           __hip_bfloat16* __restrict__ z) {
  const int tid = threadIdx.x;
  const int lane = tid & 63;
  const int wv = tid >> 6;
  const int col = lane & 15;
  const int quad = lane >> 4;
  const int kb = quad * 8;

  // effA B-fragments: 5 n-tiles covering n=(k*25+w) in [0,80)
  bf16x8 bA[5];
#pragma unroll
  for (int nt = 0; nt < 5; nt++)
    bA[nt] = *(const bf16x8*)(effAB + (nt * 16 + col) * 32 + kb);

  const int g = blockIdx.x * 4 + wv;            // global pixel
  const int n0 = g >> 8, t = g & 255;
  const float* xbase = x + (size_t)(n0 * 64) * 6400 + (size_t)t * 25;
  __hip_bfloat16* zrow0 = z + (size_t)g * 25 * 192;

#pragma unroll
  for (int mt = 0; mt < 4; mt++) {
    const int ci = mt * 16 + col;
    const float* xr = xbase + (size_t)ci * 6400;
    // A-frag: m=ci(col), k=v=kb+j ; v>=25 zero-padded
    bf16x8 xa;
    if (quad < 3) {
      floatx4u a = *(const floatx4u*)(xr + kb);
      floatx4u c = *(const floatx4u*)(xr + kb + 4);
      xa = (bf16x8){(__bf16)a.x, (__bf16)a.y, (__bf16)a.z, (__bf16)a.w,
                    (__bf16)c.x, (__bf16)c.y, (__bf16)c.z, (__bf16)c.w};
    } else {
      float v24 = xr[24];
      xa = (bf16x8){(__bf16)v24, (__bf16)0.f, (__bf16)0.f, (__bf16)0.f,
                    (__bf16)0.f, (__bf16)0.f, (__bf16)0.f, (__bf16)0.f};
    }
    floatx4 zacc[5];
#pragma unroll
    for (int nt = 0; nt < 5; nt++) {
      zacc[nt] = (floatx4){0.f, 0.f, 0.f, 0.f};
      zacc[nt] = __builtin_amdgcn_mfma_f32_16x16x32_bf16(xa, bA[nt], zacc[nt], 0, 0, 0);
    }
    // C/D: col(n)=lane&15 -> nn ; row(ci)=mt*16+quad*4+r.  Write B-operand layout:
    // z[(g*25+w)*192 + k*64 + ci]
#pragma unroll
    for (int nt = 0; nt < 5; nt++) {
      int nn = nt * 16 + col;
      if (nn < 75) {
        int k = (nn * 41) >> 10;     // floor(nn/25), exact for nn<1024
        int w = nn - k * 25;
        bf16x4 zb = (bf16x4){(__bf16)zacc[nt][0], (__bf16)zacc[nt][1],
                             (__bf16)zacc[nt][2], (__bf16)zacc[nt][3]};
        *(bf16x4*)(zrow0 + (size_t)w * 192 + k * 64 + mt * 16 + quad * 4) = zb;
      }
    }
  }
}

// ---------------- kernel 2: out = Wp @ z + bias2  (no LDS, no barrier) ----------------
// 512 thr = 8 waves; wave wv owns m-tile wv (c in [16wv,16wv+16)); block owns 64 cols.
__global__ __launch_bounds__(512, 4)
void sgc_out(const __hip_bfloat16* __restrict__ z,
             const __hip_bfloat16* __restrict__ Wp,
             const float* __restrict__ bias2,
             float* __restrict__ out) {
  const int tid = threadIdx.x;
  const int lane = tid & 63;
  const int wv = tid >> 6;
  const int col = lane & 15;
  const int quad = lane >> 4;
  const int kb = quad * 8;
  const int cg0 = blockIdx.x * 64;

  // A-fragments: W' rows c = wv*16 + col, K=192 (6 steps)
  bf16x8 afr[6];
  {
    const __hip_bfloat16* wrow = Wp + (wv * 16 + col) * 192;
#pragma unroll
    for (int ks = 0; ks < 6; ks++)
      afr[ks] = *(const bf16x8*)(wrow + ks * 32 + kb);
  }

  // accumulators init with bias2[c*25 + w]
  floatx4 acc[4];
#pragma unroll
  for (int nt = 0; nt < 4; nt++) {
    int cg = cg0 + nt * 16 + col;
    int w = cg % 25;
    int c0 = wv * 16 + quad * 4;
#pragma unroll
    for (int r = 0; r < 4; r++)
      acc[nt][r] = bias2[(c0 + r) * 25 + w];
  }

  // K-loop: B-frags straight from global z (L2/L3-resident, dense 64B segments)
#pragma unroll
  for (int ks = 0; ks < 6; ks++) {
    bf16x8 bfr[4];
#pragma unroll
    for (int nt = 0; nt < 4; nt++)
      bfr[nt] = *(const bf16x8*)(z + (size_t)(cg0 + nt * 16 + col) * 192 + ks * 32 + kb);
#pragma unroll
    for (int nt = 0; nt < 4; nt++)
      acc[nt] = __builtin_amdgcn_mfma_f32_16x16x32_bf16(afr[ks], bfr[nt], acc[nt], 0, 0, 0);
  }

  // epilogue: C/D col=lane&15 (cg), row=quad*4+r (c); out[n][c][t][w]
#pragma unroll
  for (int nt = 0; nt < 4; nt++) {
    int cg = cg0 + nt * 16 + col;
    int pix = cg / 25;
    int w = cg - pix * 25;
    int n = pix >> 8, t = pix & 255;
    int c0 = wv * 16 + quad * 4;
    size_t base = ((size_t)(n * 128 + c0) * 256 + t) * 25 + w;
#pragma unroll
    for (int r = 0; r < 4; r++)
      out[base + (size_t)r * 6400] = acc[nt][r];
  }
}

extern "C" void kernel_launch(void* const* d_in, const int* in_sizes, int n_in,
                              void* d_out, int out_size, void* d_ws, size_t ws_size,
                              hipStream_t stream) {
  const float* x    = (const float*)d_in[0];
  const float* W    = (const float*)d_in[1];
  const float* b    = (const float*)d_in[2];
  const float* A    = (const float*)d_in[3];
  const float* edge = (const float*)d_in[4];
  const float* adA  = (const float*)d_in[5];
  float* out = (float*)d_out;

  char* ws = (char*)d_ws;
  __hip_bfloat16* Wp    = (__hip_bfloat16*)ws;           // 49152 B
  __hip_bfloat16* effAB = (__hip_bfloat16*)(ws + 49152); // 5120 B
  float* bias2          = (float*)(ws + 54272);          // 12800 B
  __hip_bfloat16* z     = (__hip_bfloat16*)(ws + 67584); // 16384*192*2 = 6291456 B

  sgc_prep<<<64, 256, 0, stream>>>(W, b, A, edge, adA, Wp, effAB, bias2);
  sgc_z<<<4096, 256, 0, stream>>>(x, effAB, z);
  sgc_out<<<6400, 512, 0, stream>>>(z, Wp, bias2, out);
}